// Round 12
// baseline (820.931 us; speedup 1.0000x reference)
//
#include <hip/hip_runtime.h>

#define HW 28
#define NPIX 784
#define NB 512
#define PADW2 34                 // row stride in float2 (cols -3..30) = 272 B (16B mult)
#define PADH 34                  // rows -3..30
#define IMG_F2 (PADH * PADW2)    // 1156 float2 = 9248 B

typedef float v2f __attribute__((ext_vector_type(2)));

// ---------------------------------------------------------------------------
// 7x2 output tile per thread. Per row: 4 ds_read_b128 (8 float2 taps).
// W = (qw, ew) = (w*e^{aw}, e^{aw}); out = sum((ev,pv).(qw,ew)) / sum(ev*ew)
// ---------------------------------------------------------------------------
__device__ __forceinline__ void conv2col(const float2* sbuf,
                                         const float2* wlds,   // LDS, 16B-aligned
                                         int R0, int c, float o0[7], float o1[7])
{
    v2f W[49];
    {
        const float4* wp = (const float4*)wlds;    // broadcast, conflict-free
#pragma unroll
        for (int k = 0; k < 24; ++k) {
            float4 q = wp[k];
            W[2 * k]     = (v2f){q.x, q.y};
            W[2 * k + 1] = (v2f){q.z, q.w};
        }
        float2 lastw = wlds[48];
        W[48] = (v2f){lastw.x, lastw.y};
    }

    v2f   sN0[7], sN1[7];
    float sD0[7], sD1[7];
#pragma unroll
    for (int r = 0; r < 7; ++r) {
        sN0[r] = (v2f){0.f, 0.f}; sN1[r] = (v2f){0.f, 0.f};
        sD0[r] = 0.f; sD1[r] = 0.f;
    }
#pragma unroll
    for (int rr = 0; rr < 13; ++rr) {
        const float4* rq = (const float4*)(sbuf + (R0 + rr) * PADW2 + 2 * c);
        float4 q0 = rq[0], q1 = rq[1], q2 = rq[2], q3 = rq[3];
        v2f tp[8] = {{q0.x, q0.y}, {q0.z, q0.w}, {q1.x, q1.y}, {q1.z, q1.w},
                     {q2.x, q2.y}, {q2.z, q2.w}, {q3.x, q3.y}, {q3.z, q3.w}};
#pragma unroll
        for (int r = 0; r < 7; ++r) {
            if (r > rr || rr - r > 6) continue;     // compile-time fold
            const int di = rr - r;
#pragma unroll
            for (int t = 0; t < 7; ++t) {
                v2f wq = W[di * 7 + t];             // (qw, ew)
                sN0[r] = __builtin_elementwise_fma(tp[t],     wq, sN0[r]);
                sN1[r] = __builtin_elementwise_fma(tp[t + 1], wq, sN1[r]);
                sD0[r] = fmaf(tp[t][0],     wq[1], sD0[r]);
                sD1[r] = fmaf(tp[t + 1][0], wq[1], sD1[r]);
            }
        }
    }
#pragma unroll
    for (int r = 0; r < 7; ++r) {
        o0[r] = (sN0[r][0] + sN0[r][1]) * __builtin_amdgcn_rcpf(sD0[r]);
        o1[r] = (sN1[r][0] + sN1[r][1]) * __builtin_amdgcn_rcpf(sD1[r]);
    }
}

__device__ __forceinline__ float sigmoidf_(float s) {
    return __builtin_amdgcn_rcpf(1.f + __expf(-s));
}

// ---------------------------------------------------------------------------
// FULLY FUSED, 8 waves/block, ONE BRANCH PER WAVE, one block per image.
// Each wave: stage evpv -> conv1 -> in-place stage-2 evpv -> conv2 -> pool
// (all barrier-free, wave-internal ordering). Pool sum carried in registers
// across barrier #1; feat/h1/h2 alias the then-dead wtab area. Then inline MLP.
// LDS 80,384 B/block -> 2 blocks/CU = 16 waves/CU = 4 waves/SIMD (2x r11).
// Grid 512 = exactly co-resident. launch_bounds(512,4) caps VGPR at 128.
// ---------------------------------------------------------------------------
__global__ __launch_bounds__(512, 4) void smorph_net_kernel(
    const float* __restrict__ x,       // [512,784]
    const float* __restrict__ sw,      // [8,2,49]
    const float* __restrict__ sa,      // [8,2]
    const float* __restrict__ W1, const float* __restrict__ b1,
    const float* __restrict__ W2, const float* __restrict__ b2,
    const float* __restrict__ W3, const float* __restrict__ b3,
    float* __restrict__ out)           // [512,10]
{
    __shared__ __align__(16) float2 bufs[8][IMG_F2];   // 73,984 B
    __shared__ __align__(16) float2 wtab[8][2][50];    //  6,400 B (16B-aligned subtables)

    const int b    = blockIdx.x;       // 512 blocks
    const int tid  = threadIdx.x;      // 0..511
    const int f    = tid >> 6;         // wave = branch
    const int lane = tid & 63;

    float2* buf = bufs[f];
    const float* src = x + (size_t)b * NPIX;

    const float a1 = sa[f * 2 + 0];
    const float a2 = sa[f * 2 + 1];

    // per-branch weight tables (wave-local writes; program order protects)
    if (lane < 49) {
        float w1v = sw[(f * 2 + 0) * 49 + lane];
        float e1  = __expf(a1 * w1v);
        wtab[f][0][lane] = make_float2(w1v * e1, e1);
        float w2v = sw[(f * 2 + 1) * 49 + lane];
        float e2  = __expf(a2 * w2v);
        wtab[f][1][lane] = make_float2(w2v * e2, e2);
    }

    // phase 0: buf = padded (ev,pv); borders (1,0)  (SAME zero-pad)
    for (int idx = lane; idx < IMG_F2; idx += 64) {
        int pi = idx / PADW2;
        int pj = idx - pi * PADW2;
        float2 val = make_float2(1.f, 0.f);
        if (pi >= 3 && pi < 31 && pj >= 3 && pj < 31) {
            float v = src[(pi - 3) * HW + (pj - 3)];
            float e = __expf(a1 * v);
            val = make_float2(e, v * e);
        }
        buf[idx] = val;
    }

    const bool act = (lane < 56);
    const int s  = lane / 14;          // strip (output rows 7s..7s+6)
    const int c  = lane - s * 14;      // column pair 0..13
    const int R0 = 7 * s;
    const int j2 = 2 * c;

    float o0[7], o1[7];
    if (act) conv2col(buf, wtab[f][0], R0, c, o0, o1);

    // stage-2 (ev,pv) overwrite interior in place (own-wave conv1 reads done)
    if (act) {
#pragma unroll
        for (int r = 0; r < 7; ++r) {
            float e0 = __expf(a2 * o0[r]);
            float e1 = __expf(a2 * o1[r]);
            buf[(R0 + r + 3) * PADW2 + (j2 + 3)] = make_float2(e0, o0[r] * e0);
            buf[(R0 + r + 3) * PADW2 + (j2 + 4)] = make_float2(e1, o1[r] * e1);
        }
    }

    if (act) conv2col(buf, wtab[f][1], R0, c, o0, o1);

    // dense 28x28 plane aliased over own buf
    float* outp = (float*)buf;
    if (act) {
#pragma unroll
        for (int r = 0; r < 7; ++r) {
            outp[(R0 + r) * HW + j2]     = o0[r];
            outp[(R0 + r) * HW + j2 + 1] = o1[r];
        }
    }

    // 4x4 mean pool -> REGISTER (feat write must wait: it aliases wtab)
    float poolsum = 0.f;
    if (lane < 49) {
        int pi = lane / 7;
        int pj = lane - pi * 7;
#pragma unroll
        for (int di = 0; di < 4; ++di)
#pragma unroll
            for (int dj = 0; dj < 4; ++dj)
                poolsum += outp[(pi * 4 + di) * HW + (pj * 4 + dj)];
        poolsum *= 0.0625f;
    }
    __syncthreads();                    // all convs done; wtab now dead

    // feat/h1/h2 alias the wtab region (2,384 B needed, 6,400 available)
    float* feat = (float*)&wtab[0][0][0];
    float* h1   = feat + 392;           // offset 1568 B (16B mult)
    float* h2   = h1 + 120;             // offset 2048 B (16B mult)

    if (lane < 49) feat[f * 49 + lane] = poolsum;
    __syncthreads();

    // ---- inline MLP ----
    if (tid < 240) {
        int n = tid >> 1, h = tid & 1;
        const float4* wr = (const float4*)(W1 + n * 392);
        const float4* fv = (const float4*)feat;
        float c0 = 0.f, c1 = 0.f, c2 = 0.f, c3 = 0.f;
#pragma unroll 7
        for (int k = h; k < 98; k += 2) {
            float4 w = wr[k];
            float4 v = fv[k];
            c0 = fmaf(w.x, v.x, c0);
            c1 = fmaf(w.y, v.y, c1);
            c2 = fmaf(w.z, v.z, c2);
            c3 = fmaf(w.w, v.w, c3);
        }
        float acc = (c0 + c1) + (c2 + c3);
        acc += __shfl_xor(acc, 1);
        if (h == 0) h1[n] = sigmoidf_(acc + b1[n]);
    }
    __syncthreads();

    if (tid < 168) {
        int n = tid >> 1, h = tid & 1;
        const float4* wr = (const float4*)(W2 + n * 120);
        const float4* hv = (const float4*)h1;
        float c0 = 0.f, c1 = 0.f, c2 = 0.f, c3 = 0.f;
#pragma unroll
        for (int k = h; k < 30; k += 2) {
            float4 w = wr[k];
            float4 v = hv[k];
            c0 = fmaf(w.x, v.x, c0);
            c1 = fmaf(w.y, v.y, c1);
            c2 = fmaf(w.z, v.z, c2);
            c3 = fmaf(w.w, v.w, c3);
        }
        float acc = (c0 + c1) + (c2 + c3);
        acc += __shfl_xor(acc, 1);
        if (h == 0) h2[n] = sigmoidf_(acc + b2[n]);
    }
    __syncthreads();

    if (tid < 40) {
        int n = tid >> 2, q = tid & 3;
        const float4* wr = (const float4*)(W3 + n * 84);
        const float4* hv = (const float4*)h2;
        float c0 = 0.f, c1 = 0.f, c2 = 0.f, c3 = 0.f;
        for (int k = q; k < 21; k += 4) {
            float4 w = wr[k];
            float4 v = hv[k];
            c0 = fmaf(w.x, v.x, c0);
            c1 = fmaf(w.y, v.y, c1);
            c2 = fmaf(w.z, v.z, c2);
            c3 = fmaf(w.w, v.w, c3);
        }
        float acc = (c0 + c1) + (c2 + c3);
        acc += __shfl_xor(acc, 1);
        acc += __shfl_xor(acc, 2);
        if (q == 0) out[(size_t)b * 10 + n] = sigmoidf_(acc + b3[n]);
    }
}

extern "C" void kernel_launch(void* const* d_in, const int* in_sizes, int n_in,
                              void* d_out, int out_size, void* d_ws, size_t ws_size,
                              hipStream_t stream) {
    const float* x  = (const float*)d_in[0];
    const float* sw = (const float*)d_in[1];
    const float* sa = (const float*)d_in[2];
    const float* W1 = (const float*)d_in[3];
    const float* b1 = (const float*)d_in[4];
    const float* W2 = (const float*)d_in[5];
    const float* b2 = (const float*)d_in[6];
    const float* W3 = (const float*)d_in[7];
    const float* b3 = (const float*)d_in[8];
    float* out = (float*)d_out;

    smorph_net_kernel<<<NB, 512, 0, stream>>>(x, sw, sa, W1, b1, W2, b2, W3, b3, out);
}

// Round 13
// 120.357 us; speedup vs baseline: 6.8208x; 6.8208x over previous
//
#include <hip/hip_runtime.h>

#define HW 28
#define NPIX 784
#define NB 512
#define PADW2 34                 // row stride in float2 (cols -3..30) = 272 B (16B mult)
#define PADH 34                  // rows -3..30
#define IMG_F2 (PADH * PADW2)    // 1156 float2 = 9248 B

typedef float v2f __attribute__((ext_vector_type(2)));

// ---------------------------------------------------------------------------
// 7x2 output tile per thread. Per row: 4 ds_read_b128 (8 float2 taps).
// W = (qw, ew) = (w*e^{aw}, e^{aw}); out = sum((ev,pv).(qw,ew)) / sum(ev*ew)
// ---------------------------------------------------------------------------
__device__ __forceinline__ void conv2col(const float2* sbuf,
                                         const float2* wlds,   // LDS, 16B-aligned
                                         int R0, int c, float o0[7], float o1[7])
{
    v2f W[49];
    {
        const float4* wp = (const float4*)wlds;    // broadcast, conflict-free
#pragma unroll
        for (int k = 0; k < 24; ++k) {
            float4 q = wp[k];
            W[2 * k]     = (v2f){q.x, q.y};
            W[2 * k + 1] = (v2f){q.z, q.w};
        }
        float2 lastw = wlds[48];
        W[48] = (v2f){lastw.x, lastw.y};
    }

    v2f   sN0[7], sN1[7];
    float sD0[7], sD1[7];
#pragma unroll
    for (int r = 0; r < 7; ++r) {
        sN0[r] = (v2f){0.f, 0.f}; sN1[r] = (v2f){0.f, 0.f};
        sD0[r] = 0.f; sD1[r] = 0.f;
    }
#pragma unroll
    for (int rr = 0; rr < 13; ++rr) {
        const float4* rq = (const float4*)(sbuf + (R0 + rr) * PADW2 + 2 * c);
        float4 q0 = rq[0], q1 = rq[1], q2 = rq[2], q3 = rq[3];
        v2f tp[8] = {{q0.x, q0.y}, {q0.z, q0.w}, {q1.x, q1.y}, {q1.z, q1.w},
                     {q2.x, q2.y}, {q2.z, q2.w}, {q3.x, q3.y}, {q3.z, q3.w}};
#pragma unroll
        for (int r = 0; r < 7; ++r) {
            if (r > rr || rr - r > 6) continue;     // compile-time fold
            const int di = rr - r;
#pragma unroll
            for (int t = 0; t < 7; ++t) {
                v2f wq = W[di * 7 + t];             // (qw, ew)
                sN0[r] = __builtin_elementwise_fma(tp[t],     wq, sN0[r]);
                sN1[r] = __builtin_elementwise_fma(tp[t + 1], wq, sN1[r]);
                sD0[r] = fmaf(tp[t][0],     wq[1], sD0[r]);
                sD1[r] = fmaf(tp[t + 1][0], wq[1], sD1[r]);
            }
        }
    }
#pragma unroll
    for (int r = 0; r < 7; ++r) {
        o0[r] = (sN0[r][0] + sN0[r][1]) * __builtin_amdgcn_rcpf(sD0[r]);
        o1[r] = (sN1[r][0] + sN1[r][1]) * __builtin_amdgcn_rcpf(sD1[r]);
    }
}

__device__ __forceinline__ float sigmoidf_(float s) {
    return __builtin_amdgcn_rcpf(1.f + __expf(-s));
}

// ---------------------------------------------------------------------------
// FULLY FUSED, 8 waves/block, ONE BRANCH PER WAVE, one block per image.
// Each wave: stage evpv -> conv1 -> in-place stage-2 evpv -> conv2 -> pool
// (all barrier-free, wave-internal ordering). Pool sums cross barrier #1 in
// registers; feat/h1/h2 alias the then-dead wtab area. Then inline MLP.
// LDS 80,384 B/block -> 2 blocks/CU = 16 waves/CU = 4 waves/SIMD.
// __launch_bounds__ 2nd arg is MIN BLOCKS PER CU (CUDA semantics — r12
// post-mortem: (512,4) forced VGPR=64 and 2.7 GB of scratch spill traffic).
// (512,2) -> 16 waves/CU -> VGPR cap 128, the proven-workable allocation.
// ---------------------------------------------------------------------------
__global__ __launch_bounds__(512, 2) void smorph_net_kernel(
    const float* __restrict__ x,       // [512,784]
    const float* __restrict__ sw,      // [8,2,49]
    const float* __restrict__ sa,      // [8,2]
    const float* __restrict__ W1, const float* __restrict__ b1,
    const float* __restrict__ W2, const float* __restrict__ b2,
    const float* __restrict__ W3, const float* __restrict__ b3,
    float* __restrict__ out)           // [512,10]
{
    __shared__ __align__(16) float2 bufs[8][IMG_F2];   // 73,984 B
    __shared__ __align__(16) float2 wtab[8][2][50];    //  6,400 B (16B-aligned subtables)

    const int b    = blockIdx.x;       // 512 blocks
    const int tid  = threadIdx.x;      // 0..511
    const int f    = tid >> 6;         // wave = branch
    const int lane = tid & 63;

    float2* buf = bufs[f];
    const float* src = x + (size_t)b * NPIX;

    const float a1 = sa[f * 2 + 0];
    const float a2 = sa[f * 2 + 1];

    // per-branch weight tables (wave-local writes; program order protects)
    if (lane < 49) {
        float w1v = sw[(f * 2 + 0) * 49 + lane];
        float e1  = __expf(a1 * w1v);
        wtab[f][0][lane] = make_float2(w1v * e1, e1);
        float w2v = sw[(f * 2 + 1) * 49 + lane];
        float e2  = __expf(a2 * w2v);
        wtab[f][1][lane] = make_float2(w2v * e2, e2);
    }

    // phase 0: buf = padded (ev,pv); borders (1,0)  (SAME zero-pad)
    for (int idx = lane; idx < IMG_F2; idx += 64) {
        int pi = idx / PADW2;
        int pj = idx - pi * PADW2;
        float2 val = make_float2(1.f, 0.f);
        if (pi >= 3 && pi < 31 && pj >= 3 && pj < 31) {
            float v = src[(pi - 3) * HW + (pj - 3)];
            float e = __expf(a1 * v);
            val = make_float2(e, v * e);
        }
        buf[idx] = val;
    }

    const bool act = (lane < 56);
    const int s  = lane / 14;          // strip (output rows 7s..7s+6)
    const int c  = lane - s * 14;      // column pair 0..13
    const int R0 = 7 * s;
    const int j2 = 2 * c;

    float o0[7], o1[7];
    if (act) conv2col(buf, wtab[f][0], R0, c, o0, o1);

    // stage-2 (ev,pv) overwrite interior in place (own-wave conv1 reads done)
    if (act) {
#pragma unroll
        for (int r = 0; r < 7; ++r) {
            float e0 = __expf(a2 * o0[r]);
            float e1 = __expf(a2 * o1[r]);
            buf[(R0 + r + 3) * PADW2 + (j2 + 3)] = make_float2(e0, o0[r] * e0);
            buf[(R0 + r + 3) * PADW2 + (j2 + 4)] = make_float2(e1, o1[r] * e1);
        }
    }

    if (act) conv2col(buf, wtab[f][1], R0, c, o0, o1);

    // dense 28x28 plane aliased over own buf
    float* outp = (float*)buf;
    if (act) {
#pragma unroll
        for (int r = 0; r < 7; ++r) {
            outp[(R0 + r) * HW + j2]     = o0[r];
            outp[(R0 + r) * HW + j2 + 1] = o1[r];
        }
    }

    // 4x4 mean pool -> REGISTER (feat write must wait: it aliases wtab)
    float poolsum = 0.f;
    if (lane < 49) {
        int pi = lane / 7;
        int pj = lane - pi * 7;
#pragma unroll
        for (int di = 0; di < 4; ++di)
#pragma unroll
            for (int dj = 0; dj < 4; ++dj)
                poolsum += outp[(pi * 4 + di) * HW + (pj * 4 + dj)];
        poolsum *= 0.0625f;
    }
    __syncthreads();                    // all convs done; wtab now dead

    // feat/h1/h2 alias the wtab region (2,384 B needed, 6,400 available)
    float* feat = (float*)&wtab[0][0][0];
    float* h1   = feat + 392;           // offset 1568 B (16B mult)
    float* h2   = h1 + 120;             // offset 2048 B (16B mult)

    if (lane < 49) feat[f * 49 + lane] = poolsum;
    __syncthreads();

    // ---- inline MLP ----
    if (tid < 240) {
        int n = tid >> 1, h = tid & 1;
        const float4* wr = (const float4*)(W1 + n * 392);
        const float4* fv = (const float4*)feat;
        float c0 = 0.f, c1 = 0.f, c2 = 0.f, c3 = 0.f;
#pragma unroll 7
        for (int k = h; k < 98; k += 2) {
            float4 w = wr[k];
            float4 v = fv[k];
            c0 = fmaf(w.x, v.x, c0);
            c1 = fmaf(w.y, v.y, c1);
            c2 = fmaf(w.z, v.z, c2);
            c3 = fmaf(w.w, v.w, c3);
        }
        float acc = (c0 + c1) + (c2 + c3);
        acc += __shfl_xor(acc, 1);
        if (h == 0) h1[n] = sigmoidf_(acc + b1[n]);
    }
    __syncthreads();

    if (tid < 168) {
        int n = tid >> 1, h = tid & 1;
        const float4* wr = (const float4*)(W2 + n * 120);
        const float4* hv = (const float4*)h1;
        float c0 = 0.f, c1 = 0.f, c2 = 0.f, c3 = 0.f;
#pragma unroll
        for (int k = h; k < 30; k += 2) {
            float4 w = wr[k];
            float4 v = hv[k];
            c0 = fmaf(w.x, v.x, c0);
            c1 = fmaf(w.y, v.y, c1);
            c2 = fmaf(w.z, v.z, c2);
            c3 = fmaf(w.w, v.w, c3);
        }
        float acc = (c0 + c1) + (c2 + c3);
        acc += __shfl_xor(acc, 1);
        if (h == 0) h2[n] = sigmoidf_(acc + b2[n]);
    }
    __syncthreads();

    if (tid < 40) {
        int n = tid >> 2, q = tid & 3;
        const float4* wr = (const float4*)(W3 + n * 84);
        const float4* hv = (const float4*)h2;
        float c0 = 0.f, c1 = 0.f, c2 = 0.f, c3 = 0.f;
        for (int k = q; k < 21; k += 4) {
            float4 w = wr[k];
            float4 v = hv[k];
            c0 = fmaf(w.x, v.x, c0);
            c1 = fmaf(w.y, v.y, c1);
            c2 = fmaf(w.z, v.z, c2);
            c3 = fmaf(w.w, v.w, c3);
        }
        float acc = (c0 + c1) + (c2 + c3);
        acc += __shfl_xor(acc, 1);
        acc += __shfl_xor(acc, 2);
        if (q == 0) out[(size_t)b * 10 + n] = sigmoidf_(acc + b3[n]);
    }
}

extern "C" void kernel_launch(void* const* d_in, const int* in_sizes, int n_in,
                              void* d_out, int out_size, void* d_ws, size_t ws_size,
                              hipStream_t stream) {
    const float* x  = (const float*)d_in[0];
    const float* sw = (const float*)d_in[1];
    const float* sa = (const float*)d_in[2];
    const float* W1 = (const float*)d_in[3];
    const float* b1 = (const float*)d_in[4];
    const float* W2 = (const float*)d_in[5];
    const float* b2 = (const float*)d_in[6];
    const float* W3 = (const float*)d_in[7];
    const float* b3 = (const float*)d_in[8];
    float* out = (float*)d_out;

    smorph_net_kernel<<<NB, 512, 0, stream>>>(x, sw, sa, W1, b1, W2, b2, W3, b3, out);
}